// Round 10
// baseline (271.923 us; speedup 1.0000x reference)
//
#include <hip/hip_runtime.h>
#include <cstdint>

#pragma clang fp contract(off)

#define BB 64
#define PP 32768
#define OO 50
#define THRESH_F 0.5f
#define VAR0 0.1f
#define VAR1 0.2f
#define NEGPOS_I 3
#define SS 32            // k_ml grid.x
#define T1 4             // priors per thread in k_ml
#define NB_P0 256        // pass-0 bins: exponent byte (bits 30:23)
#define NB_P1 4096       // pass-1 bins: bits 22:11
#define NB_P2 2048       // pass-2 bins: bits 10:0
#define NCELL 1024       // 4 size-classes x 16x16 Morton cells
#define PREPB 32         // k_prep blocks

typedef unsigned long long u64;

// ---- spatial cell of a prior: 4-bit x / 4-bit y Morton + size class ----
__device__ __forceinline__ unsigned mpart4(unsigned x) {
    x = (x | (x << 2)) & 0x33u;
    x = (x | (x << 1)) & 0x55u;
    return x;
}
__device__ __forceinline__ int cell_of(float4 pr) {
    int xb = (int)(pr.x * 16.0f); xb = xb < 0 ? 0 : (xb > 15 ? 15 : xb);
    int yb = (int)(pr.y * 16.0f); yb = yb < 0 ? 0 : (yb > 15 ? 15 : yb);
    float s = fmaxf(pr.z, pr.w);
    int wc = s < 0.275f ? 0 : (s < 0.368f ? 1 : (s < 0.44f ? 2 : 3));
    return wc * 256 + (int)(mpart4((unsigned)xb) | (mpart4((unsigned)yb) << 1));
}

// ---- K0: fused prep. Each block: (a) zeroes a disjoint slice of the
// atomically-accumulated region (only read by LATER kernels -> no race);
// (b) LDS-histograms ALL priors, tracking prefix counts for its own
// 1024-prior slice; (c) scans; (d) scatters its slice into per-block
// per-cell disjoint ranges. perm is a bijection by construction. ----
__global__ void __launch_bounds__(512)
k_prep(const float4* __restrict__ pri, int* __restrict__ perm, int* __restrict__ iperm,
       float4* __restrict__ zdst, int zn4) {
    __shared__ int cnt[NCELL];
    __shared__ int pref[NCELL];
    __shared__ int scn[512];
    int tid = threadIdx.x, blk = blockIdx.x;
    for (int i = blk * 512 + tid; i < zn4; i += PREPB * 512)
        zdst[i] = make_float4(0.f, 0.f, 0.f, 0.f);
    cnt[tid] = 0; cnt[tid + 512] = 0;
    pref[tid] = 0; pref[tid + 512] = 0;
    __syncthreads();
    int pstart = blk * (PP / PREPB);     // 1024-prior slice
    for (int p = tid; p < PP; p += 512) {
        int c = cell_of(pri[p]);
        atomicAdd(&cnt[c], 1);
        if (p < pstart) atomicAdd(&pref[c], 1);
    }
    __syncthreads();
    // exclusive scan over 1024 cells (thread owns cells 2t, 2t+1)
    int a0 = cnt[2 * tid], a1 = cnt[2 * tid + 1];
    int s = a0 + a1;
    scn[tid] = s; __syncthreads();
    for (int off = 1; off < 512; off <<= 1) {
        int v = (tid >= off) ? scn[tid - off] : 0;
        __syncthreads(); scn[tid] += v; __syncthreads();
    }
    int excl = scn[tid] - s;
    // cursor start = global cell base + count of same-cell priors before slice
    cnt[2 * tid]     = excl + pref[2 * tid];
    cnt[2 * tid + 1] = excl + a0 + pref[2 * tid + 1];
    __syncthreads();
    for (int k = 0; k < 2; ++k) {
        int p = pstart + tid * 2 + k;
        int c = cell_of(pri[p]);
        int pos = atomicAdd(&cnt[c], 1);
        perm[pos] = p;
        iperm[p] = pos;
    }
}

// wave64 reduce via DPP (identity old): row_shr 1/2/4/8, row_bcast15 (rows
// 1,3), row_bcast31 (rows 2,3). Result in lane 63.
#define DPP_MAX(x, ctrl, rmask)                                              \
    {                                                                        \
        int _o = __float_as_int(x);                                          \
        x = fmaxf(x, __int_as_float(__builtin_amdgcn_update_dpp(             \
                _o, _o, (ctrl), (rmask), 0xf, false)));                      \
    }
#define DPP_MINF(x, ctrl, rmask)                                             \
    {                                                                        \
        int _o = __float_as_int(x);                                          \
        x = fminf(x, __int_as_float(__builtin_amdgcn_update_dpp(             \
                _o, _o, (ctrl), (rmask), 0xf, false)));                      \
    }
#define WAVE_MAXF(x) { DPP_MAX(x,0x111,0xf); DPP_MAX(x,0x112,0xf); DPP_MAX(x,0x114,0xf); \
                       DPP_MAX(x,0x118,0xf); DPP_MAX(x,0x142,0xa); DPP_MAX(x,0x143,0xc); }
#define WAVE_MINF(x) { DPP_MINF(x,0x111,0xf); DPP_MINF(x,0x112,0xf); DPP_MINF(x,0x114,0xf); \
                       DPP_MINF(x,0x118,0xf); DPP_MINF(x,0x142,0xa); DPP_MINF(x,0x143,0xc); }

// smooth-L1 of (arm_loc - encode(truth, prior)) — shared by k_ml and k_fix.
__device__ __forceinline__ float sl1enc(const float* __restrict__ tb,
                                        float4 pr, float4 ld) {
    float gx = ((tb[0] + tb[2]) * 0.5f - pr.x) / (VAR0 * pr.z);
    float gy = ((tb[1] + tb[3]) * 0.5f - pr.y) / (VAR0 * pr.w);
    float gw = logf((tb[2] - tb[0]) / pr.z) / VAR1;
    float gh = logf((tb[3] - tb[1]) / pr.w) / VAR1;
    float g[4] = {gx, gy, gw, gh};
    float l[4] = {ld.x, ld.y, ld.z, ld.w};
    float s = 0.f;
    for (int q = 0; q < 4; ++q) {
        float d = l[q] - g[q];
        float ad = fabsf(d);
        s += (ad < 1.0f) ? 0.5f * d * d : ad - 0.5f;
    }
    return s;
}

// ---- K1: fused matcher + loss (byte-identical logic to round 9) ----
__global__ void __launch_bounds__(256, 8)
k_ml(const float* __restrict__ priors, const int* __restrict__ perm,
     const float* __restrict__ targets,
     const float* __restrict__ arm_loc, const float* __restrict__ arm_conf,
     float* __restrict__ lcmP, unsigned char* __restrict__ bpiP,
     u64* __restrict__ bpm,
     float* __restrict__ pll, float* __restrict__ pplc, int* __restrict__ pnp,
     int* __restrict__ Hc0, float* __restrict__ Hs0) {
    __shared__ float4 trP[OO];      // {x0,y0,x1,y1}
    __shared__ float2 trQ[OO];      // {area, raw label}
    __shared__ int   hc[4 * NB_P0];
    __shared__ float hs[4 * NB_P0];
    __shared__ float s1[256]; __shared__ float s2[256]; __shared__ int s3[256];
    // XCD co-location swizzle: same-batch blocks share (x % 8) -> same XCD.
    int b = (blockIdx.x % 8) * 8 + (blockIdx.y % 8);
    int s = (blockIdx.x / 8) + 4 * (blockIdx.y / 8);
    int tid = threadIdx.x;
    if (tid < OO) {
        const float* tb = &targets[(size_t)(b * OO + tid) * 5];
        float x0 = tb[0], y0 = tb[1], x1 = tb[2], y1 = tb[3];
        trP[tid] = make_float4(x0, y0, x1, y1);
        trQ[tid] = make_float2((x1 - x0) * (y1 - y0), tb[4]);
    }
    for (int i = tid; i < 4 * NB_P0; i += 256) { hc[i] = 0; hs[i] = 0.f; }
    __syncthreads();

    int p0 = s * (256 * T1) + tid * T1;
    int4 o4 = ((const int4*)perm)[p0 >> 2];
    int o_[T1] = {o4.x, o4.y, o4.z, o4.w};
    int omin = min(min(o_[0], o_[1]), min(o_[2], o_[3]));
    float bx0[T1], by0[T1], bx1[T1], by1[T1], aB[T1];
#pragma unroll
    for (int j = 0; j < T1; ++j) {
        float4 pr = ((const float4*)priors)[o_[j]];
        bx0[j] = pr.x - pr.z * 0.5f; by0[j] = pr.y - pr.w * 0.5f;
        bx1[j] = pr.x + pr.z * 0.5f; by1[j] = pr.y + pr.w * 0.5f;
        aB[j] = (bx1[j] - bx0[j]) * (by1[j] - by0[j]);
    }
    float lx0 = fminf(fminf(bx0[0], bx0[1]), fminf(bx0[2], bx0[3]));
    float ly0 = fminf(fminf(by0[0], by0[1]), fminf(by0[2], by0[3]));
    float lx1 = fmaxf(fmaxf(bx1[0], bx1[1]), fmaxf(bx1[2], bx1[3]));
    float ly1 = fmaxf(fmaxf(by1[0], by1[1]), fmaxf(by1[2], by1[3]));
    WAVE_MINF(lx0); WAVE_MINF(ly0); WAVE_MAXF(lx1); WAVE_MAXF(ly1);
    float wx0 = __int_as_float(__builtin_amdgcn_readlane(__float_as_int(lx0), 63));
    float wy0 = __int_as_float(__builtin_amdgcn_readlane(__float_as_int(ly0), 63));
    float wx1 = __int_as_float(__builtin_amdgcn_readlane(__float_as_int(lx1), 63));
    float wy1 = __int_as_float(__builtin_amdgcn_readlane(__float_as_int(ly1), 63));

    float rbv[T1]; int rbi[T1];
#pragma unroll
    for (int j = 0; j < T1; ++j) { rbv[j] = 0.0f; rbi[j] = 0; }

    for (int t = 0; t < OO; ++t) {
        float4 tP = trP[t];
        if (!(tP.z > wx0 && tP.x < wx1 && tP.w > wy0 && tP.y < wy1)) continue;
        float aA = trQ[t].x;
        float I[T1];
#pragma unroll
        for (int j = 0; j < T1; ++j) {
            float ltx = fmaxf(tP.x, bx0[j]), lty = fmaxf(tP.y, by0[j]);
            float rbx = fminf(tP.z, bx1[j]), rby = fminf(tP.w, by1[j]);
            float wx = fmaxf(rbx - ltx, 0.f), wy = fmaxf(rby - lty, 0.f);
            I[j] = wx * wy;
        }
        bool anyl = (I[0] > 0.f) | (I[1] > 0.f) | (I[2] > 0.f) | (I[3] > 0.f);
        if (__any(anyl)) {
            float cbv = 0.0f; int cbo = omin;
#pragma unroll
            for (int j = 0; j < T1; ++j) {
                float v = I[j] / (aA + aB[j] - I[j]);
                if (v > rbv[j]) { rbv[j] = v; rbi[j] = t; }   // row: first-max
                if (v > cbv || (v == cbv && o_[j] < cbo)) { cbv = v; cbo = o_[j]; }
            }
            float x = cbv;
            WAVE_MAXF(x);
            float mvf = __int_as_float(__builtin_amdgcn_readlane(__float_as_int(x), 63));
            if (mvf > 0.0f) {
                u64 msk = __ballot(cbv == mvf);
                int ln = (int)__ffsll((long long)msk) - 1;
                int morig = __builtin_amdgcn_readlane(cbo, ln);
                u64 rest = msk & (msk - 1);
                while (rest) {            // rare: exact cross-lane ties
                    int l2 = (int)__ffsll((long long)rest) - 1;
                    int o2 = __builtin_amdgcn_readlane(cbo, l2);
                    morig = min(morig, o2);
                    rest &= rest - 1;
                }
                if ((tid & 63) == 0) {
                    u64 pk = ((u64)__float_as_uint(mvf) << 32) | (unsigned)(PP - morig);
                    atomicMax(&bpm[b * OO + t], pk);
                }
            }
        }
    }

    size_t bbase = (size_t)b * PP;
    int hb = (tid >> 6) * NB_P0;       // this wave's sub-histogram
    float ll = 0.0f, plc = 0.0f; int np = 0;
    float outv[4]; unsigned pbyte = 0;
#pragma unroll
    for (int c = 0; c < T1; ++c) {
        int o = o_[c]; size_t bo = bbase + o;
        int ti = rbi[c]; float ov = rbv[c];
        float2 cf = ((const float2*)arm_conf)[bo];
        float c0 = cf.x, c1 = cf.y;
        float m = fmaxf(c0, c1);
        float lse = logf(expf(c0 - m) + expf(c1 - m)) + m;
        bool pos = (ov >= THRESH_F) && (trQ[ti].y >= 0.0f);
        float lc = lse - (pos ? c1 : c0);
        outv[c] = pos ? 0.0f : lc;
        pbyte |= (unsigned)((pos ? 0x80u : 0u) | (unsigned)ti) << (8 * c);
        unsigned u = __float_as_uint(outv[c]);
        atomicAdd(&hc[hb + (u >> 23)], 1);
        atomicAdd(&hs[hb + (u >> 23)], outv[c]);
        if (pos) {
            np++; plc += lc;
            float4 pr = ((const float4*)priors)[o];
            float4 ld = ((const float4*)arm_loc)[bo];
            const float4 tv = trP[ti];
            float tb4[4] = {tv.x, tv.y, tv.z, tv.w};
            ll += sl1enc(tb4, pr, ld);
        }
    }
    size_t bq = bbase + p0;
    ((float4*)lcmP)[bq >> 2] = make_float4(outv[0], outv[1], outv[2], outv[3]);
    ((unsigned*)bpiP)[bq >> 2] = pbyte;

    __syncthreads();
    {
        int cv = hc[tid] + hc[NB_P0 + tid] + hc[2*NB_P0 + tid] + hc[3*NB_P0 + tid];
        if (cv) {
            float sv = hs[tid] + hs[NB_P0 + tid] + hs[2*NB_P0 + tid] + hs[3*NB_P0 + tid];
            atomicAdd(&Hc0[b * NB_P0 + tid], cv);
            atomicAdd(&Hs0[b * NB_P0 + tid], sv);
        }
    }
    s1[tid] = ll; s2[tid] = plc; s3[tid] = np;
    __syncthreads();
    for (int st = 128; st > 0; st >>= 1) {
        if (tid < st) { s1[tid] += s1[tid+st]; s2[tid] += s2[tid+st]; s3[tid] += s3[tid+st]; }
        __syncthreads();
    }
    if (tid == 0) {
        pll[s * BB + b] = s1[0];
        pplc[s * BB + b] = s2[0];
        pnp[s * BB + b] = s3[0];
    }
}

// ---- K2: forced-match fixup. Patches lcmP + hist; emits COMPLETE per-batch
// sums llb/plcb/npb (partials + deltas). ----
__global__ void k_fix(const u64* __restrict__ bpm, const float* __restrict__ targets,
                      const float* __restrict__ arm_loc, const float* __restrict__ arm_conf,
                      const float* __restrict__ priors, const int* __restrict__ iperm,
                      const unsigned char* __restrict__ bpiP, float* __restrict__ lcmP,
                      const float* __restrict__ pll, const float* __restrict__ pplc,
                      const int* __restrict__ pnp,
                      float* __restrict__ llb, float* __restrict__ plcb,
                      int* __restrict__ npb,
                      int* __restrict__ Hc0, float* __restrict__ Hs0) {
    int b = blockIdx.x, j = threadIdx.x;   // 64 threads, one wave
    int p = -1;
    if (j < OO) {
        unsigned lo = (unsigned)(bpm[b * OO + j] & 0xFFFFFFFFull);
        p = lo ? (PP - (int)lo) : 0;   // all-zero column -> first prior
    }
    bool w = (j < OO);
    for (int jj = 1; jj < OO; ++jj) {
        int pj = __shfl(p, jj, 64);
        if (jj > j && pj == p) w = false;
    }
    float dll = 0.f, dplc = 0.f; int dnp = 0;
    if (w) {
        int pos_ = iperm[p];
        size_t bq = (size_t)b * PP + pos_;   // permuted (lcm/bpi) address
        size_t bo = (size_t)b * PP + p;      // original (conf/loc) address
        unsigned char ob = bpiP[bq];
        bool old_pos = (ob & 0x80u) != 0;
        int old_ti = ob & 63;
        float2 cf = ((const float2*)arm_conf)[bo];
        float c0 = cf.x, c1 = cf.y;
        float m = fmaxf(c0, c1);
        float lse = logf(expf(c0 - m) + expf(c1 - m)) + m;
        const float* tbj = &targets[(size_t)(b * OO + j) * 5];
        bool new_pos = (tbj[4] >= 0.0f);
        float old_lcm = lcmP[bq];
        float new_lcm = new_pos ? 0.0f : (lse - c0);
        unsigned uo = __float_as_uint(old_lcm), un = __float_as_uint(new_lcm);
        if (uo != un) {
            atomicAdd(&Hc0[b * NB_P0 + (uo >> 23)], -1);
            atomicAdd(&Hs0[b * NB_P0 + (uo >> 23)], -old_lcm);
            atomicAdd(&Hc0[b * NB_P0 + (un >> 23)], 1);
            atomicAdd(&Hs0[b * NB_P0 + (un >> 23)], new_lcm);
            lcmP[bq] = new_lcm;
        }
        float4 pr = ((const float4*)priors)[p];
        float4 ld = ((const float4*)arm_loc)[bo];
        if (old_pos) {
            dnp -= 1; dplc -= (lse - c1);
            dll -= sl1enc(&targets[(size_t)(b * OO + old_ti) * 5], pr, ld);
        }
        if (new_pos) {
            dnp += 1; dplc += (lse - c1);
            dll += sl1enc(tbj, pr, ld);
        }
    }
    float myll = (j < SS) ? pll[j * BB + b] : 0.f;
    float mypl = (j < SS) ? pplc[j * BB + b] : 0.f;
    int   mynp = (j < SS) ? pnp[j * BB + b] : 0;
    dll += myll; dplc += mypl; dnp += mynp;
    for (int st = 32; st >= 1; st >>= 1) {
        dll += __shfl_down(dll, st, 64);
        dplc += __shfl_down(dplc, st, 64);
        dnp += __shfl_down(dnp, st, 64);
    }
    if (j == 0) {
        llb[b] = dll;
        plcb[b] = dplc;
        npb[b] = dnp;
    }
}

// ---- K3: 3-pass radix selection + final cross-batch reduction. One block
// per batch; last ticket re-reads totals (acquire via atomicAdd(p,0)) and
// writes out. ----
__global__ void __launch_bounds__(256)
k_sel(const float* __restrict__ lcmP,
      const float* __restrict__ llb, const float* __restrict__ plcb,
      const int* __restrict__ npb,
      const int* __restrict__ Hc0, const float* __restrict__ Hs0,
      float* __restrict__ gacc, int* __restrict__ gcnt,
      float* __restrict__ out) {
    __shared__ int hc[NB_P1]; __shared__ float hs[NB_P1];
    __shared__ int sc[256]; __shared__ float sf[256];
    __shared__ int s_chunk, s_r; __shared__ float s_S; __shared__ unsigned s_pref;
    int b = blockIdx.x, tid = threadIdx.x;
    const float4* v4 = (const float4*)(lcmP + (size_t)b * PP);

    {   // pass 0: scan 256-bin global exponent hist (one bin per thread)
        int c = Hc0[b * NB_P0 + tid];
        float f = Hs0[b * NB_P0 + tid];
        sc[tid] = c; sf[tid] = f;
        if (tid == 0) {
            int k = NEGPOS_I * npb[b]; if (k > PP - 1) k = PP - 1;
            s_r = k; s_S = 0.f;
        }
        __syncthreads();
        for (int off = 1; off < 256; off <<= 1) {
            int cv = (tid + off < 256) ? sc[tid + off] : 0;
            float fv = (tid + off < 256) ? sf[tid + off] : 0.f;
            __syncthreads(); sc[tid] += cv; sf[tid] += fv; __syncthreads();
        }
        int r = s_r;
        int nxt = (tid == 255) ? 0 : sc[tid + 1];
        if (sc[tid] >= r && nxt < r) s_chunk = tid;
        __syncthreads();
        if (tid == 0) {
            int ch = s_chunk;
            s_pref = (unsigned)ch;
            s_r = r - ((ch == 255) ? 0 : sc[ch + 1]);
            s_S = (ch == 255) ? 0.f : sf[ch + 1];
        }
        __syncthreads();
    }
    {   // pass 1: bits 22:11 (4096 bins) where exponent byte == pref
        for (int i = tid; i < NB_P1; i += 256) { hc[i] = 0; hs[i] = 0.f; }
        __syncthreads();
        unsigned pref = s_pref;
        for (int it = 0; it < 32; ++it) {
            float4 x = v4[it * 256 + tid];
            float xs[4] = {x.x, x.y, x.z, x.w};
            for (int c2 = 0; c2 < 4; ++c2) {
                unsigned u = __float_as_uint(xs[c2]);
                if ((u >> 23) == pref) {
                    atomicAdd(&hc[(u >> 11) & 4095u], 1);
                    atomicAdd(&hs[(u >> 11) & 4095u], xs[c2]);
                }
            }
        }
        __syncthreads();
        int c = 0; float f = 0.f; int base = tid * 16;
        for (int i = 0; i < 16; ++i) { c += hc[base + i]; f += hs[base + i]; }
        sc[tid] = c; sf[tid] = f; __syncthreads();
        for (int off = 1; off < 256; off <<= 1) {
            int cv = (tid + off < 256) ? sc[tid + off] : 0;
            float fv = (tid + off < 256) ? sf[tid + off] : 0.f;
            __syncthreads(); sc[tid] += cv; sf[tid] += fv; __syncthreads();
        }
        int r = s_r;
        int nxt = (tid == 255) ? 0 : sc[tid + 1];
        if (sc[tid] >= r && nxt < r) s_chunk = tid;
        __syncthreads();
        if (tid == 0) {
            int ch = s_chunk;
            int r2 = r - ((ch == 255) ? 0 : sc[ch + 1]);
            float S2 = s_S + ((ch == 255) ? 0.f : sf[ch + 1]);
            int binSel = ch * 16;
            for (int i = 15; i >= 0; --i) {
                int bin = ch * 16 + i; int cbn = hc[bin];
                if (r2 <= cbn) { binSel = bin; break; }
                r2 -= cbn; S2 += hs[bin];
            }
            s_pref = (s_pref << 12) | (unsigned)binSel; s_r = r2; s_S = S2;
        }
        __syncthreads();
    }
    {   // pass 2: bits 10:0 (2048 bins) where bits 30:11 == pref
        for (int i = tid; i < NB_P2; i += 256) { hc[i] = 0; hs[i] = 0.f; }
        __syncthreads();
        unsigned pref = s_pref;
        for (int it = 0; it < 32; ++it) {
            float4 x = v4[it * 256 + tid];
            float xs[4] = {x.x, x.y, x.z, x.w};
            for (int c2 = 0; c2 < 4; ++c2) {
                unsigned u = __float_as_uint(xs[c2]);
                if ((u >> 11) == pref) {
                    atomicAdd(&hc[u & 2047u], 1);
                    atomicAdd(&hs[u & 2047u], xs[c2]);
                }
            }
        }
        __syncthreads();
        int c = 0; float f = 0.f; int base = tid * 8;
        for (int i = 0; i < 8; ++i) { c += hc[base + i]; f += hs[base + i]; }
        sc[tid] = c; sf[tid] = f; __syncthreads();
        for (int off = 1; off < 256; off <<= 1) {
            int cv = (tid + off < 256) ? sc[tid + off] : 0;
            float fv = (tid + off < 256) ? sf[tid + off] : 0.f;
            __syncthreads(); sc[tid] += cv; sf[tid] += fv; __syncthreads();
        }
        int r = s_r;
        int nxt = (tid == 255) ? 0 : sc[tid + 1];
        if (sc[tid] >= r && nxt < r) s_chunk = tid;
        __syncthreads();
        if (tid == 0) {
            int ch = s_chunk;
            int r2 = r - ((ch == 255) ? 0 : sc[ch + 1]);
            float S2 = s_S + ((ch == 255) ? 0.f : sf[ch + 1]);
            int binSel = ch * 8;
            for (int i = 7; i >= 0; --i) {
                int bin = ch * 8 + i; int cbn = hc[bin];
                if (r2 <= cbn) { binSel = bin; break; }
                r2 -= cbn; S2 += hs[bin];
            }
            unsigned tb = (s_pref << 11) | (unsigned)binSel;
            float tval = __uint_as_float(tb);
            float ccb = plcb[b] + S2 + (float)r2 * tval;
            float llv = llb[b]; int npv = npb[b];
            atomicAdd(&gacc[0], llv);
            atomicAdd(&gacc[1], ccb);
            atomicAdd(&gcnt[0], npv);
            __threadfence();
            int tk = atomicAdd(&gcnt[1], 1);
            if (tk == BB - 1) {
                __threadfence();
                float llt = atomicAdd(&gacc[0], 0.f);   // coherent re-read
                float cct = atomicAdd(&gacc[1], 0.f);
                int npt = atomicAdd(&gcnt[0], 0);
                float N = (float)npt;
                out[0] = llt / N;
                out[1] = cct / N;
            }
        }
    }
}

extern "C" void kernel_launch(void* const* d_in, const int* in_sizes, int n_in,
                              void* d_out, int out_size, void* d_ws, size_t ws_size,
                              hipStream_t stream) {
    const float* arm_loc  = (const float*)d_in[0];
    const float* arm_conf = (const float*)d_in[1];
    const float* priors   = (const float*)d_in[4];
    const float* targets  = (const float*)d_in[5];
    float* out = (float*)d_out;

    char* w = (char*)d_ws;
    float* lcmP = (float*)w;  w += sizeof(float) * (size_t)BB * PP;   // 8 MB
    unsigned char* bpiP = (unsigned char*)w; w += (size_t)BB * PP;    // 2 MB
    // ---- zeroed region (atomically accumulated; zeroed by k_prep) ----
    char* zbase = w;
    int*   Hc0 = (int*)w;    w += sizeof(int)   * BB * NB_P0;
    float* Hs0 = (float*)w;  w += sizeof(float) * BB * NB_P0;
    u64*   bpm = (u64*)w;    w += sizeof(u64)   * BB * OO;
    float* gacc = (float*)w; w += sizeof(float) * 2;   // ll, cc totals
    int*   gcnt = (int*)w;   w += sizeof(int)   * 2;   // np total, ticket
    size_t zbytes = (size_t)(w - zbase);
    // ---- plain written-before-read region ----
    int*   perm  = (int*)w;  w += sizeof(int) * PP;
    int*   iperm = (int*)w;  w += sizeof(int) * PP;
    float* pll  = (float*)w; w += sizeof(float) * BB * SS;
    float* pplc = (float*)w; w += sizeof(float) * BB * SS;
    int*   pnp  = (int*)w;   w += sizeof(int)   * BB * SS;
    float* llb  = (float*)w; w += sizeof(float) * BB;
    float* plcb = (float*)w; w += sizeof(float) * BB;
    int*   npb  = (int*)w;   w += sizeof(int)   * BB;

    int zn4 = (int)(zbytes / 16);
    k_prep<<<PREPB, 512, 0, stream>>>((const float4*)priors, perm, iperm,
                                      (float4*)zbase, zn4);
    k_ml<<<dim3(SS, BB), 256, 0, stream>>>(priors, perm, targets, arm_loc, arm_conf,
                                           lcmP, bpiP, bpm, pll, pplc, pnp, Hc0, Hs0);
    k_fix<<<BB, 64, 0, stream>>>(bpm, targets, arm_loc, arm_conf, priors, iperm,
                                 bpiP, lcmP, pll, pplc, pnp, llb, plcb, npb, Hc0, Hs0);
    k_sel<<<BB, 256, 0, stream>>>(lcmP, llb, plcb, npb, Hc0, Hs0, gacc, gcnt, out);
}

// Round 11
// 252.785 us; speedup vs baseline: 1.0757x; 1.0757x over previous
//
#include <hip/hip_runtime.h>
#include <cstdint>

#pragma clang fp contract(off)

#define BB 64
#define PP 32768
#define OO 50
#define THRESH_F 0.5f
#define VAR0 0.1f
#define VAR1 0.2f
#define NEGPOS_I 3
#define SS 32            // k_ml grid.x
#define T1 4             // priors per thread in k_ml
#define NB_P0 256        // pass-0 bins: exponent byte (bits 30:23)
#define NB_P1 4096       // pass-1 bins: bits 22:11
#define NB_P2 2048       // pass-2 bins: bits 10:0
#define NCELL 1024       // 4 size-classes x 16x16 Morton cells

typedef unsigned long long u64;

// ---- spatial cell of a prior: 4-bit x / 4-bit y Morton + size class ----
__device__ __forceinline__ unsigned mpart4(unsigned x) {
    x = (x | (x << 2)) & 0x33u;
    x = (x | (x << 1)) & 0x55u;
    return x;
}
__device__ __forceinline__ int cell_of(float4 pr) {
    int xb = (int)(pr.x * 16.0f); xb = xb < 0 ? 0 : (xb > 15 ? 15 : xb);
    int yb = (int)(pr.y * 16.0f); yb = yb < 0 ? 0 : (yb > 15 ? 15 : yb);
    float s = fmaxf(pr.z, pr.w);
    int wc = s < 0.275f ? 0 : (s < 0.368f ? 1 : (s < 0.44f ? 2 : 3));
    return wc * 256 + (int)(mpart4((unsigned)xb) | (mpart4((unsigned)yb) << 1));
}

// ---- K0: zero the atomically-accumulated region ----
__global__ void k_zero(float4* __restrict__ dst, int n4) {
    int i = blockIdx.x * blockDim.x + threadIdx.x;
    if (i < n4) dst[i] = make_float4(0.f, 0.f, 0.f, 0.f);
}

// ---- prep: histogram priors into cells (32 blocks) ----
__global__ void k_phist(const float4* __restrict__ pri, int* __restrict__ cnt) {
    int p = blockIdx.x * 1024 + threadIdx.x * 4;
    for (int j = 0; j < 4; ++j)
        atomicAdd(&cnt[cell_of(pri[p + j])], 1);
}

// ---- prep: replicated scan of cell counts + scatter (perm & iperm) ----
__global__ void __launch_bounds__(256)
k_pss(const float4* __restrict__ pri, const int* __restrict__ cnt,
      int* __restrict__ cursor, int* __restrict__ perm, int* __restrict__ iperm) {
    __shared__ int sc[256];
    __shared__ int sbase[NCELL];
    int tid = threadIdx.x;
    int a[4]; int s = 0;
    for (int i = 0; i < 4; ++i) { a[i] = cnt[tid * 4 + i]; s += a[i]; }
    sc[tid] = s; __syncthreads();
    for (int off = 1; off < 256; off <<= 1) {
        int v = (tid >= off) ? sc[tid - off] : 0;
        __syncthreads(); sc[tid] += v; __syncthreads();
    }
    int excl = sc[tid] - s;
    for (int i = 0; i < 4; ++i) { sbase[tid * 4 + i] = excl; excl += a[i]; }
    __syncthreads();
    int p = blockIdx.x * 1024 + tid * 4;
    for (int j = 0; j < 4; ++j) {
        int c = cell_of(pri[p + j]);
        int pos = sbase[c] + atomicAdd(&cursor[c], 1);
        perm[pos] = p + j;
        iperm[p + j] = pos;
    }
}

// wave64 reduce via DPP (identity old): row_shr 1/2/4/8, row_bcast15 (rows
// 1,3), row_bcast31 (rows 2,3). Result in lane 63.
#define DPP_MAX(x, ctrl, rmask)                                              \
    {                                                                        \
        int _o = __float_as_int(x);                                          \
        x = fmaxf(x, __int_as_float(__builtin_amdgcn_update_dpp(             \
                _o, _o, (ctrl), (rmask), 0xf, false)));                      \
    }
#define DPP_MINF(x, ctrl, rmask)                                             \
    {                                                                        \
        int _o = __float_as_int(x);                                          \
        x = fminf(x, __int_as_float(__builtin_amdgcn_update_dpp(             \
                _o, _o, (ctrl), (rmask), 0xf, false)));                      \
    }
#define WAVE_MAXF(x) { DPP_MAX(x,0x111,0xf); DPP_MAX(x,0x112,0xf); DPP_MAX(x,0x114,0xf); \
                       DPP_MAX(x,0x118,0xf); DPP_MAX(x,0x142,0xa); DPP_MAX(x,0x143,0xc); }
#define WAVE_MINF(x) { DPP_MINF(x,0x111,0xf); DPP_MINF(x,0x112,0xf); DPP_MINF(x,0x114,0xf); \
                       DPP_MINF(x,0x118,0xf); DPP_MINF(x,0x142,0xa); DPP_MINF(x,0x143,0xc); }

// smooth-L1 of (arm_loc - encode(truth, prior)) — shared by k_ml and k_fix.
__device__ __forceinline__ float sl1enc(const float* __restrict__ tb,
                                        float4 pr, float4 ld) {
    float gx = ((tb[0] + tb[2]) * 0.5f - pr.x) / (VAR0 * pr.z);
    float gy = ((tb[1] + tb[3]) * 0.5f - pr.y) / (VAR0 * pr.w);
    float gw = logf((tb[2] - tb[0]) / pr.z) / VAR1;
    float gh = logf((tb[3] - tb[1]) / pr.w) / VAR1;
    float g[4] = {gx, gy, gw, gh};
    float l[4] = {ld.x, ld.y, ld.z, ld.w};
    float s = 0.f;
    for (int q = 0; q < 4; ++q) {
        float d = l[q] - g[q];
        float ad = fabsf(d);
        s += (ad < 1.0f) ? 0.5f * d * d : ad - 0.5f;
    }
    return s;
}

// ---- K1: fused matcher + loss over spatially-clustered priors. Wave-uniform
// survive mask (computed ONCE, 64-lane parallel) replaces the per-truth bbox
// test; t iterates set bits ascending -> identical order & semantics. ----
__global__ void __launch_bounds__(256, 8)
k_ml(const float* __restrict__ priors, const int* __restrict__ perm,
     const float* __restrict__ targets,
     const float* __restrict__ arm_loc, const float* __restrict__ arm_conf,
     float* __restrict__ lcmP, unsigned char* __restrict__ bpiP,
     u64* __restrict__ bpm,
     float* __restrict__ pll, float* __restrict__ pplc, int* __restrict__ pnp,
     int* __restrict__ Hc0, float* __restrict__ Hs0) {
    __shared__ float4 trP[OO];      // {x0,y0,x1,y1}
    __shared__ float2 trQ[OO];      // {area, raw label}
    __shared__ int   hc[4 * NB_P0];
    __shared__ float hs[4 * NB_P0];
    __shared__ float s1[256]; __shared__ float s2[256]; __shared__ int s3[256];
    // XCD co-location swizzle: same-batch blocks share (x % 8) -> same XCD.
    int b = (blockIdx.x % 8) * 8 + (blockIdx.y % 8);
    int s = (blockIdx.x / 8) + 4 * (blockIdx.y / 8);
    int tid = threadIdx.x;
    if (tid < OO) {
        const float* tb = &targets[(size_t)(b * OO + tid) * 5];
        float x0 = tb[0], y0 = tb[1], x1 = tb[2], y1 = tb[3];
        trP[tid] = make_float4(x0, y0, x1, y1);
        trQ[tid] = make_float2((x1 - x0) * (y1 - y0), tb[4]);
    }
    for (int i = tid; i < 4 * NB_P0; i += 256) { hc[i] = 0; hs[i] = 0.f; }
    __syncthreads();

    int p0 = s * (256 * T1) + tid * T1;
    int4 o4 = ((const int4*)perm)[p0 >> 2];
    int o_[T1] = {o4.x, o4.y, o4.z, o4.w};
    int omin = min(min(o_[0], o_[1]), min(o_[2], o_[3]));
    float bx0[T1], by0[T1], bx1[T1], by1[T1], aB[T1];
#pragma unroll
    for (int j = 0; j < T1; ++j) {
        float4 pr = ((const float4*)priors)[o_[j]];
        bx0[j] = pr.x - pr.z * 0.5f; by0[j] = pr.y - pr.w * 0.5f;
        bx1[j] = pr.x + pr.z * 0.5f; by1[j] = pr.y + pr.w * 0.5f;
        aB[j] = (bx1[j] - bx0[j]) * (by1[j] - by0[j]);
    }
    // wave bounding box of the 256 owned priors (uniform via readlane)
    float lx0 = fminf(fminf(bx0[0], bx0[1]), fminf(bx0[2], bx0[3]));
    float ly0 = fminf(fminf(by0[0], by0[1]), fminf(by0[2], by0[3]));
    float lx1 = fmaxf(fmaxf(bx1[0], bx1[1]), fmaxf(bx1[2], bx1[3]));
    float ly1 = fmaxf(fmaxf(by1[0], by1[1]), fmaxf(by1[2], by1[3]));
    WAVE_MINF(lx0); WAVE_MINF(ly0); WAVE_MAXF(lx1); WAVE_MAXF(ly1);
    float wx0 = __int_as_float(__builtin_amdgcn_readlane(__float_as_int(lx0), 63));
    float wy0 = __int_as_float(__builtin_amdgcn_readlane(__float_as_int(ly0), 63));
    float wx1 = __int_as_float(__builtin_amdgcn_readlane(__float_as_int(lx1), 63));
    float wy1 = __int_as_float(__builtin_amdgcn_readlane(__float_as_int(ly1), 63));

    // one-time 64-lane-parallel truth-vs-wave-bbox test -> wave-uniform mask
    u64 smask;
    {
        int lane = tid & 63;
        bool sv = false;
        if (lane < OO) {
            float4 tt = trP[lane];
            sv = (tt.z > wx0 && tt.x < wx1 && tt.w > wy0 && tt.y < wy1);
        }
        smask = __ballot(sv);
    }

    float rbv[T1]; int rbi[T1];
#pragma unroll
    for (int j = 0; j < T1; ++j) { rbv[j] = 0.0f; rbi[j] = 0; }

    for (u64 mm = smask; mm; mm &= mm - 1) {
        int t = (int)__ffsll((long long)mm) - 1;    // ascending t order
        float4 tP = trP[t];
        float aA = trQ[t].x;
        float I[T1];
#pragma unroll
        for (int j = 0; j < T1; ++j) {
            float ltx = fmaxf(tP.x, bx0[j]), lty = fmaxf(tP.y, by0[j]);
            float rbx = fminf(tP.z, bx1[j]), rby = fminf(tP.w, by1[j]);
            float wx = fmaxf(rbx - ltx, 0.f), wy = fmaxf(rby - lty, 0.f);
            I[j] = wx * wy;
        }
        bool anyl = (I[0] > 0.f) | (I[1] > 0.f) | (I[2] > 0.f) | (I[3] > 0.f);
        if (__any(anyl)) {
            float cbv = 0.0f; int cbo = omin;
#pragma unroll
            for (int j = 0; j < T1; ++j) {
                float v = I[j] / (aA + aB[j] - I[j]);
                if (v > rbv[j]) { rbv[j] = v; rbi[j] = t; }   // row: first-max
                if (v > cbv || (v == cbv && o_[j] < cbo)) { cbv = v; cbo = o_[j]; }
            }
            float x = cbv;
            WAVE_MAXF(x);
            float mvf = __int_as_float(__builtin_amdgcn_readlane(__float_as_int(x), 63));
            if (mvf > 0.0f) {
                u64 msk = __ballot(cbv == mvf);
                int ln = (int)__ffsll((long long)msk) - 1;
                int morig = __builtin_amdgcn_readlane(cbo, ln);
                u64 rest = msk & (msk - 1);
                while (rest) {            // rare: exact cross-lane ties
                    int l2 = (int)__ffsll((long long)rest) - 1;
                    int o2 = __builtin_amdgcn_readlane(cbo, l2);
                    morig = min(morig, o2);
                    rest &= rest - 1;
                }
                if ((tid & 63) == 0) {
                    u64 pk = ((u64)__float_as_uint(mvf) << 32) | (unsigned)(PP - morig);
                    atomicMax(&bpm[b * OO + t], pk);
                }
            }
        }
    }

    // ---- epilogue: loss for the un-forced matching; per-wave exponent hist ----
    size_t bbase = (size_t)b * PP;
    int hb = (tid >> 6) * NB_P0;       // this wave's sub-histogram
    float ll = 0.0f, plc = 0.0f; int np = 0;
    float outv[4]; unsigned pbyte = 0;
#pragma unroll
    for (int c = 0; c < T1; ++c) {
        int o = o_[c]; size_t bo = bbase + o;
        int ti = rbi[c]; float ov = rbv[c];
        float2 cf = ((const float2*)arm_conf)[bo];
        float c0 = cf.x, c1 = cf.y;
        float m = fmaxf(c0, c1);
        float lse = logf(expf(c0 - m) + expf(c1 - m)) + m;
        bool pos = (ov >= THRESH_F) && (trQ[ti].y >= 0.0f);
        float lc = lse - (pos ? c1 : c0);
        outv[c] = pos ? 0.0f : lc;
        pbyte |= (unsigned)((pos ? 0x80u : 0u) | (unsigned)ti) << (8 * c);
        unsigned u = __float_as_uint(outv[c]);
        atomicAdd(&hc[hb + (u >> 23)], 1);
        atomicAdd(&hs[hb + (u >> 23)], outv[c]);
        if (pos) {
            np++; plc += lc;
            float4 pr = ((const float4*)priors)[o];
            float4 ld = ((const float4*)arm_loc)[bo];
            const float4 tv = trP[ti];
            float tb4[4] = {tv.x, tv.y, tv.z, tv.w};
            ll += sl1enc(tb4, pr, ld);
        }
    }
    size_t bq = bbase + p0;
    ((float4*)lcmP)[bq >> 2] = make_float4(outv[0], outv[1], outv[2], outv[3]);
    ((unsigned*)bpiP)[bq >> 2] = pbyte;

    __syncthreads();
    {   // merge per-wave hists (one bin per thread)
        int cv = hc[tid] + hc[NB_P0 + tid] + hc[2*NB_P0 + tid] + hc[3*NB_P0 + tid];
        if (cv) {
            float sv = hs[tid] + hs[NB_P0 + tid] + hs[2*NB_P0 + tid] + hs[3*NB_P0 + tid];
            atomicAdd(&Hc0[b * NB_P0 + tid], cv);
            atomicAdd(&Hs0[b * NB_P0 + tid], sv);
        }
    }
    s1[tid] = ll; s2[tid] = plc; s3[tid] = np;
    __syncthreads();
    for (int st = 128; st > 0; st >>= 1) {
        if (tid < st) { s1[tid] += s1[tid+st]; s2[tid] += s2[tid+st]; s3[tid] += s3[tid+st]; }
        __syncthreads();
    }
    if (tid == 0) {
        pll[s * BB + b] = s1[0];
        pplc[s * BB + b] = s2[0];
        pnp[s * BB + b] = s3[0];
    }
}

// ---- K2: forced-match fixup (exact deltas; last truth wins on dup priors).
// Patches lcmP + the 256-bin hist + scalar partials; publishes npb. ----
__global__ void k_fix(const u64* __restrict__ bpm, const float* __restrict__ targets,
                      const float* __restrict__ arm_loc, const float* __restrict__ arm_conf,
                      const float* __restrict__ priors, const int* __restrict__ iperm,
                      const unsigned char* __restrict__ bpiP, float* __restrict__ lcmP,
                      float* __restrict__ pll, float* __restrict__ pplc,
                      int* __restrict__ pnp, int* __restrict__ npb,
                      int* __restrict__ Hc0, float* __restrict__ Hs0) {
    int b = blockIdx.x, j = threadIdx.x;   // 64 threads, one wave
    int p = -1;
    if (j < OO) {
        unsigned lo = (unsigned)(bpm[b * OO + j] & 0xFFFFFFFFull);
        p = lo ? (PP - (int)lo) : 0;   // all-zero column -> first prior
    }
    bool w = (j < OO);
    for (int jj = 1; jj < OO; ++jj) {
        int pj = __shfl(p, jj, 64);
        if (jj > j && pj == p) w = false;
    }
    float dll = 0.f, dplc = 0.f; int dnp = 0;
    if (w) {
        int pos_ = iperm[p];
        size_t bq = (size_t)b * PP + pos_;   // permuted (lcm/bpi) address
        size_t bo = (size_t)b * PP + p;      // original (conf/loc) address
        unsigned char ob = bpiP[bq];
        bool old_pos = (ob & 0x80u) != 0;
        int old_ti = ob & 63;
        float2 cf = ((const float2*)arm_conf)[bo];
        float c0 = cf.x, c1 = cf.y;
        float m = fmaxf(c0, c1);
        float lse = logf(expf(c0 - m) + expf(c1 - m)) + m;
        const float* tbj = &targets[(size_t)(b * OO + j) * 5];
        bool new_pos = (tbj[4] >= 0.0f);
        float old_lcm = lcmP[bq];
        float new_lcm = new_pos ? 0.0f : (lse - c0);
        unsigned uo = __float_as_uint(old_lcm), un = __float_as_uint(new_lcm);
        if (uo != un) {
            atomicAdd(&Hc0[b * NB_P0 + (uo >> 23)], -1);
            atomicAdd(&Hs0[b * NB_P0 + (uo >> 23)], -old_lcm);
            atomicAdd(&Hc0[b * NB_P0 + (un >> 23)], 1);
            atomicAdd(&Hs0[b * NB_P0 + (un >> 23)], new_lcm);
            lcmP[bq] = new_lcm;
        }
        float4 pr = ((const float4*)priors)[p];
        float4 ld = ((const float4*)arm_loc)[bo];
        if (old_pos) {
            dnp -= 1; dplc -= (lse - c1);
            dll -= sl1enc(&targets[(size_t)(b * OO + old_ti) * 5], pr, ld);
        }
        if (new_pos) {
            dnp += 1; dplc += (lse - c1);
            dll += sl1enc(tbj, pr, ld);
        }
    }
    int myp = (j < SS) ? pnp[j * BB + b] : 0;
    for (int st = 32; st >= 1; st >>= 1) {
        dll += __shfl_down(dll, st, 64);
        dplc += __shfl_down(dplc, st, 64);
        dnp += __shfl_down(dnp, st, 64);
        myp += __shfl_down(myp, st, 64);
    }
    if (j == 0) {
        pll[b] += dll;
        pplc[b] += dplc;
        pnp[b] += dnp;
        npb[b] = myp + dnp;
    }
}

// ---- K3: 3-pass radix selection, one block per batch. Pass 0 scans the
// 256-bin global exponent hist; passes 1/2 stream lcmP with 4-wide load
// batching (memory-level parallelism at 64-block occupancy). ----
__global__ void __launch_bounds__(256)
k_sel(const float* __restrict__ lcmP, const int* __restrict__ npb,
      const int* __restrict__ Hc0, const float* __restrict__ Hs0,
      float* __restrict__ ssum, int* __restrict__ srem, unsigned* __restrict__ stb) {
    __shared__ int hc[NB_P1]; __shared__ float hs[NB_P1];
    __shared__ int sc[256]; __shared__ float sf[256];
    __shared__ int s_chunk, s_r; __shared__ float s_S; __shared__ unsigned s_pref;
    int b = blockIdx.x, tid = threadIdx.x;
    const float4* v4 = (const float4*)(lcmP + (size_t)b * PP);

    {   // pass 0: scan 256-bin global hist (one bin per thread)
        int c = Hc0[b * NB_P0 + tid];
        float f = Hs0[b * NB_P0 + tid];
        sc[tid] = c; sf[tid] = f;
        if (tid == 0) {
            int k = NEGPOS_I * npb[b]; if (k > PP - 1) k = PP - 1;
            s_r = k; s_S = 0.f;
        }
        __syncthreads();
        for (int off = 1; off < 256; off <<= 1) {
            int cv = (tid + off < 256) ? sc[tid + off] : 0;
            float fv = (tid + off < 256) ? sf[tid + off] : 0.f;
            __syncthreads(); sc[tid] += cv; sf[tid] += fv; __syncthreads();
        }
        int r = s_r;
        int nxt = (tid == 255) ? 0 : sc[tid + 1];
        if (sc[tid] >= r && nxt < r) s_chunk = tid;
        __syncthreads();
        if (tid == 0) {
            int ch = s_chunk;
            s_pref = (unsigned)ch;
            s_r = r - ((ch == 255) ? 0 : sc[ch + 1]);
            s_S = (ch == 255) ? 0.f : sf[ch + 1];
        }
        __syncthreads();
    }
    {   // pass 1: bits 22:11 (4096 bins) where exponent byte == pref
        for (int i = tid; i < NB_P1; i += 256) { hc[i] = 0; hs[i] = 0.f; }
        __syncthreads();
        unsigned pref = s_pref;
        for (int it = 0; it < 8; ++it) {
            float4 xs4[4];
#pragma unroll
            for (int q = 0; q < 4; ++q) xs4[q] = v4[it * 1024 + q * 256 + tid];
#pragma unroll
            for (int q = 0; q < 4; ++q) {
                float xs[4] = {xs4[q].x, xs4[q].y, xs4[q].z, xs4[q].w};
                for (int c2 = 0; c2 < 4; ++c2) {
                    unsigned u = __float_as_uint(xs[c2]);
                    if ((u >> 23) == pref) {
                        atomicAdd(&hc[(u >> 11) & 4095u], 1);
                        atomicAdd(&hs[(u >> 11) & 4095u], xs[c2]);
                    }
                }
            }
        }
        __syncthreads();
        int c = 0; float f = 0.f; int base = tid * 16;
        for (int i = 0; i < 16; ++i) { c += hc[base + i]; f += hs[base + i]; }
        sc[tid] = c; sf[tid] = f; __syncthreads();
        for (int off = 1; off < 256; off <<= 1) {
            int cv = (tid + off < 256) ? sc[tid + off] : 0;
            float fv = (tid + off < 256) ? sf[tid + off] : 0.f;
            __syncthreads(); sc[tid] += cv; sf[tid] += fv; __syncthreads();
        }
        int r = s_r;
        int nxt = (tid == 255) ? 0 : sc[tid + 1];
        if (sc[tid] >= r && nxt < r) s_chunk = tid;
        __syncthreads();
        if (tid == 0) {
            int ch = s_chunk;
            int r2 = r - ((ch == 255) ? 0 : sc[ch + 1]);
            float S2 = s_S + ((ch == 255) ? 0.f : sf[ch + 1]);
            int binSel = ch * 16;
            for (int i = 15; i >= 0; --i) {
                int bin = ch * 16 + i; int cbn = hc[bin];
                if (r2 <= cbn) { binSel = bin; break; }
                r2 -= cbn; S2 += hs[bin];
            }
            s_pref = (s_pref << 12) | (unsigned)binSel; s_r = r2; s_S = S2;
        }
        __syncthreads();
    }
    {   // pass 2: bits 10:0 (2048 bins) where bits 30:11 == pref
        for (int i = tid; i < NB_P2; i += 256) { hc[i] = 0; hs[i] = 0.f; }
        __syncthreads();
        unsigned pref = s_pref;
        for (int it = 0; it < 8; ++it) {
            float4 xs4[4];
#pragma unroll
            for (int q = 0; q < 4; ++q) xs4[q] = v4[it * 1024 + q * 256 + tid];
#pragma unroll
            for (int q = 0; q < 4; ++q) {
                float xs[4] = {xs4[q].x, xs4[q].y, xs4[q].z, xs4[q].w};
                for (int c2 = 0; c2 < 4; ++c2) {
                    unsigned u = __float_as_uint(xs[c2]);
                    if ((u >> 11) == pref) {
                        atomicAdd(&hc[u & 2047u], 1);
                        atomicAdd(&hs[u & 2047u], xs[c2]);
                    }
                }
            }
        }
        __syncthreads();
        int c = 0; float f = 0.f; int base = tid * 8;
        for (int i = 0; i < 8; ++i) { c += hc[base + i]; f += hs[base + i]; }
        sc[tid] = c; sf[tid] = f; __syncthreads();
        for (int off = 1; off < 256; off <<= 1) {
            int cv = (tid + off < 256) ? sc[tid + off] : 0;
            float fv = (tid + off < 256) ? sf[tid + off] : 0.f;
            __syncthreads(); sc[tid] += cv; sf[tid] += fv; __syncthreads();
        }
        int r = s_r;
        int nxt = (tid == 255) ? 0 : sc[tid + 1];
        if (sc[tid] >= r && nxt < r) s_chunk = tid;
        __syncthreads();
        if (tid == 0) {
            int ch = s_chunk;
            int r2 = r - ((ch == 255) ? 0 : sc[ch + 1]);
            float S2 = s_S + ((ch == 255) ? 0.f : sf[ch + 1]);
            int binSel = ch * 8;
            for (int i = 7; i >= 0; --i) {
                int bin = ch * 8 + i; int cbn = hc[bin];
                if (r2 <= cbn) { binSel = bin; break; }
                r2 -= cbn; S2 += hs[bin];
            }
            stb[b] = (s_pref << 11) | (unsigned)binSel;
            srem[b] = r2; ssum[b] = S2;
        }
    }
}

// ---- K4: final reduction across batches -> (loss_l/N, loss_c/N) ----
__global__ void k_final(const float* __restrict__ pll, const float* __restrict__ pplc,
                        const int* __restrict__ pnp, const float* __restrict__ ssum,
                        const int* __restrict__ srem, const unsigned* __restrict__ stb,
                        float* __restrict__ out) {
    int b = threadIdx.x;          // 64 threads = one wave, one batch each
    float ll = 0.f, plc = 0.f; int np = 0;
    for (int s = 0; s < SS; ++s) {
        ll += pll[s * BB + b];
        plc += pplc[s * BB + b];
        np += pnp[s * BB + b];
    }
    float tval = __uint_as_float(stb[b]);
    float cc = plc + ssum[b] + (float)srem[b] * tval;
    for (int s = 32; s > 0; s >>= 1) {
        ll += __shfl_down(ll, s);
        cc += __shfl_down(cc, s);
        np += __shfl_down(np, s);
    }
    if (b == 0) {
        float N = (float)np;
        out[0] = ll / N;
        out[1] = cc / N;
    }
}

extern "C" void kernel_launch(void* const* d_in, const int* in_sizes, int n_in,
                              void* d_out, int out_size, void* d_ws, size_t ws_size,
                              hipStream_t stream) {
    const float* arm_loc  = (const float*)d_in[0];
    const float* arm_conf = (const float*)d_in[1];
    const float* priors   = (const float*)d_in[4];
    const float* targets  = (const float*)d_in[5];
    float* out = (float*)d_out;

    char* w = (char*)d_ws;
    float* lcmP = (float*)w;  w += sizeof(float) * (size_t)BB * PP;   // 8 MB
    unsigned char* bpiP = (unsigned char*)w; w += (size_t)BB * PP;    // 2 MB
    // ---- zeroed region (atomically accumulated) ----
    char* zbase = w;
    int*   Hc0 = (int*)w;    w += sizeof(int)   * BB * NB_P0;
    float* Hs0 = (float*)w;  w += sizeof(float) * BB * NB_P0;
    u64*   bpm = (u64*)w;    w += sizeof(u64)   * BB * OO;
    int*   cellCnt = (int*)w; w += sizeof(int) * NCELL;
    int*   cursor  = (int*)w; w += sizeof(int) * NCELL;
    size_t zbytes = (size_t)(w - zbase);
    // ---- plain written-before-read region ----
    int*   perm  = (int*)w;  w += sizeof(int) * PP;
    int*   iperm = (int*)w;  w += sizeof(int) * PP;
    float* pll  = (float*)w; w += sizeof(float) * BB * SS;
    float* pplc = (float*)w; w += sizeof(float) * BB * SS;
    int*   pnp  = (int*)w;   w += sizeof(int)   * BB * SS;
    int*   npb  = (int*)w;   w += sizeof(int)   * BB;
    int*      srem = (int*)w;      w += sizeof(int) * BB;
    float*    ssum = (float*)w;    w += sizeof(float) * BB;
    unsigned* stb  = (unsigned*)w; w += sizeof(unsigned) * BB;

    int n4 = (int)(zbytes / 16);
    k_zero<<<(n4 + 255) / 256, 256, 0, stream>>>((float4*)zbase, n4);
    k_phist<<<PP / 1024, 256, 0, stream>>>((const float4*)priors, cellCnt);
    k_pss<<<PP / 1024, 256, 0, stream>>>((const float4*)priors, cellCnt, cursor, perm, iperm);
    k_ml<<<dim3(SS, BB), 256, 0, stream>>>(priors, perm, targets, arm_loc, arm_conf,
                                           lcmP, bpiP, bpm, pll, pplc, pnp, Hc0, Hs0);
    k_fix<<<BB, 64, 0, stream>>>(bpm, targets, arm_loc, arm_conf, priors, iperm,
                                 bpiP, lcmP, pll, pplc, pnp, npb, Hc0, Hs0);
    k_sel<<<BB, 256, 0, stream>>>(lcmP, npb, Hc0, Hs0, ssum, srem, stb);
    k_final<<<1, 64, 0, stream>>>(pll, pplc, pnp, ssum, srem, stb, out);
}

// Round 12
// 248.870 us; speedup vs baseline: 1.0926x; 1.0157x over previous
//
#include <hip/hip_runtime.h>
#include <cstdint>

#pragma clang fp contract(off)

#define BB 64
#define PP 32768
#define OO 50
#define THRESH_F 0.5f
#define VAR0 0.1f
#define VAR1 0.2f
#define NEGPOS_I 3
#define SS 32            // k_ml grid.x
#define T1 4             // priors per thread in k_ml
#define NB_P0 256        // pass-0 bins: exponent byte (bits 30:23)
#define NB_P1 4096       // pass-1 bins: bits 22:11
#define NB_P2 2048       // pass-2 bins: bits 10:0
#define NCELL 1024       // 4 size-classes x 16x16 Morton cells

typedef unsigned long long u64;

// ---- spatial cell of a prior: 4-bit x / 4-bit y Morton + size class ----
__device__ __forceinline__ unsigned mpart4(unsigned x) {
    x = (x | (x << 2)) & 0x33u;
    x = (x | (x << 1)) & 0x55u;
    return x;
}
__device__ __forceinline__ int cell_of(float4 pr) {
    int xb = (int)(pr.x * 16.0f); xb = xb < 0 ? 0 : (xb > 15 ? 15 : xb);
    int yb = (int)(pr.y * 16.0f); yb = yb < 0 ? 0 : (yb > 15 ? 15 : yb);
    float s = fmaxf(pr.z, pr.w);
    int wc = s < 0.275f ? 0 : (s < 0.368f ? 1 : (s < 0.44f ? 2 : 3));
    return wc * 256 + (int)(mpart4((unsigned)xb) | (mpart4((unsigned)yb) << 1));
}

// ---- prep A: per-block LDS histogram of 1024 priors -> private cnt32 row
// (no global atomics -> no zero/accumulate race). Block 0 zeroes cursor. ----
__global__ void __launch_bounds__(256)
k_phist(const float4* __restrict__ pri, int* __restrict__ cnt32,
        int* __restrict__ cursor) {
    __shared__ int lc[NCELL];
    int tid = threadIdx.x, blk = blockIdx.x;
    for (int i = tid; i < NCELL; i += 256) lc[i] = 0;
    if (blk == 0)
        for (int i = tid; i < NCELL; i += 256) cursor[i] = 0;
    __syncthreads();
    int p = blk * 1024 + tid * 4;
    for (int j = 0; j < 4; ++j)
        atomicAdd(&lc[cell_of(pri[p + j])], 1);
    __syncthreads();
    for (int i = tid; i < NCELL; i += 256) cnt32[blk * NCELL + i] = lc[i];
}

// ---- prep B: sum cnt32 rows -> replicated scan -> scatter perm/iperm.
// Also zeroes the atomically-accumulated region (Hc0/Hs0/bpm/gacc/gcnt),
// which is only consumed by LATER kernels (stream-ordered, race-free). ----
__global__ void __launch_bounds__(256)
k_pss(const float4* __restrict__ pri, const int* __restrict__ cnt32,
      int* __restrict__ cursor, int* __restrict__ perm, int* __restrict__ iperm,
      float4* __restrict__ zdst, int zn4) {
    __shared__ int sc[256];
    __shared__ int sbase[NCELL];
    int tid = threadIdx.x;
    for (int i = blockIdx.x * 256 + tid; i < zn4; i += 32 * 256)
        zdst[i] = make_float4(0.f, 0.f, 0.f, 0.f);
    int a[4]; int s = 0;
    for (int i = 0; i < 4; ++i) {
        int c = tid * 4 + i;
        int v = 0;
        for (int r = 0; r < 32; ++r) v += cnt32[r * NCELL + c];
        a[i] = v; s += v;
    }
    sc[tid] = s; __syncthreads();
    for (int off = 1; off < 256; off <<= 1) {
        int v = (tid >= off) ? sc[tid - off] : 0;
        __syncthreads(); sc[tid] += v; __syncthreads();
    }
    int excl = sc[tid] - s;
    for (int i = 0; i < 4; ++i) { sbase[tid * 4 + i] = excl; excl += a[i]; }
    __syncthreads();
    int p = blockIdx.x * 1024 + tid * 4;
    for (int j = 0; j < 4; ++j) {
        int c = cell_of(pri[p + j]);
        int pos = sbase[c] + atomicAdd(&cursor[c], 1);
        perm[pos] = p + j;
        iperm[p + j] = pos;
    }
}

// wave64 reduce via DPP (identity old): row_shr 1/2/4/8, row_bcast15 (rows
// 1,3), row_bcast31 (rows 2,3). Result in lane 63.
#define DPP_MAX(x, ctrl, rmask)                                              \
    {                                                                        \
        int _o = __float_as_int(x);                                          \
        x = fmaxf(x, __int_as_float(__builtin_amdgcn_update_dpp(             \
                _o, _o, (ctrl), (rmask), 0xf, false)));                      \
    }
#define DPP_MINF(x, ctrl, rmask)                                             \
    {                                                                        \
        int _o = __float_as_int(x);                                          \
        x = fminf(x, __int_as_float(__builtin_amdgcn_update_dpp(             \
                _o, _o, (ctrl), (rmask), 0xf, false)));                      \
    }
#define WAVE_MAXF(x) { DPP_MAX(x,0x111,0xf); DPP_MAX(x,0x112,0xf); DPP_MAX(x,0x114,0xf); \
                       DPP_MAX(x,0x118,0xf); DPP_MAX(x,0x142,0xa); DPP_MAX(x,0x143,0xc); }
#define WAVE_MINF(x) { DPP_MINF(x,0x111,0xf); DPP_MINF(x,0x112,0xf); DPP_MINF(x,0x114,0xf); \
                       DPP_MINF(x,0x118,0xf); DPP_MINF(x,0x142,0xa); DPP_MINF(x,0x143,0xc); }

// smooth-L1 of (arm_loc - encode(truth, prior)) — shared by k_ml and k_fix.
__device__ __forceinline__ float sl1enc(const float* __restrict__ tb,
                                        float4 pr, float4 ld) {
    float gx = ((tb[0] + tb[2]) * 0.5f - pr.x) / (VAR0 * pr.z);
    float gy = ((tb[1] + tb[3]) * 0.5f - pr.y) / (VAR0 * pr.w);
    float gw = logf((tb[2] - tb[0]) / pr.z) / VAR1;
    float gh = logf((tb[3] - tb[1]) / pr.w) / VAR1;
    float g[4] = {gx, gy, gw, gh};
    float l[4] = {ld.x, ld.y, ld.z, ld.w};
    float s = 0.f;
    for (int q = 0; q < 4; ++q) {
        float d = l[q] - g[q];
        float ad = fabsf(d);
        s += (ad < 1.0f) ? 0.5f * d * d : ad - 0.5f;
    }
    return s;
}

// ---- K1: fused matcher + loss (round-11 verbatim) ----
__global__ void __launch_bounds__(256, 8)
k_ml(const float* __restrict__ priors, const int* __restrict__ perm,
     const float* __restrict__ targets,
     const float* __restrict__ arm_loc, const float* __restrict__ arm_conf,
     float* __restrict__ lcmP, unsigned char* __restrict__ bpiP,
     u64* __restrict__ bpm,
     float* __restrict__ pll, float* __restrict__ pplc, int* __restrict__ pnp,
     int* __restrict__ Hc0, float* __restrict__ Hs0) {
    __shared__ float4 trP[OO];      // {x0,y0,x1,y1}
    __shared__ float2 trQ[OO];      // {area, raw label}
    __shared__ int   hc[4 * NB_P0];
    __shared__ float hs[4 * NB_P0];
    __shared__ float s1[256]; __shared__ float s2[256]; __shared__ int s3[256];
    // XCD co-location swizzle: same-batch blocks share (x % 8) -> same XCD.
    int b = (blockIdx.x % 8) * 8 + (blockIdx.y % 8);
    int s = (blockIdx.x / 8) + 4 * (blockIdx.y / 8);
    int tid = threadIdx.x;
    if (tid < OO) {
        const float* tb = &targets[(size_t)(b * OO + tid) * 5];
        float x0 = tb[0], y0 = tb[1], x1 = tb[2], y1 = tb[3];
        trP[tid] = make_float4(x0, y0, x1, y1);
        trQ[tid] = make_float2((x1 - x0) * (y1 - y0), tb[4]);
    }
    for (int i = tid; i < 4 * NB_P0; i += 256) { hc[i] = 0; hs[i] = 0.f; }
    __syncthreads();

    int p0 = s * (256 * T1) + tid * T1;
    int4 o4 = ((const int4*)perm)[p0 >> 2];
    int o_[T1] = {o4.x, o4.y, o4.z, o4.w};
    int omin = min(min(o_[0], o_[1]), min(o_[2], o_[3]));
    float bx0[T1], by0[T1], bx1[T1], by1[T1], aB[T1];
#pragma unroll
    for (int j = 0; j < T1; ++j) {
        float4 pr = ((const float4*)priors)[o_[j]];
        bx0[j] = pr.x - pr.z * 0.5f; by0[j] = pr.y - pr.w * 0.5f;
        bx1[j] = pr.x + pr.z * 0.5f; by1[j] = pr.y + pr.w * 0.5f;
        aB[j] = (bx1[j] - bx0[j]) * (by1[j] - by0[j]);
    }
    // wave bounding box of the 256 owned priors (uniform via readlane)
    float lx0 = fminf(fminf(bx0[0], bx0[1]), fminf(bx0[2], bx0[3]));
    float ly0 = fminf(fminf(by0[0], by0[1]), fminf(by0[2], by0[3]));
    float lx1 = fmaxf(fmaxf(bx1[0], bx1[1]), fmaxf(bx1[2], bx1[3]));
    float ly1 = fmaxf(fmaxf(by1[0], by1[1]), fmaxf(by1[2], by1[3]));
    WAVE_MINF(lx0); WAVE_MINF(ly0); WAVE_MAXF(lx1); WAVE_MAXF(ly1);
    float wx0 = __int_as_float(__builtin_amdgcn_readlane(__float_as_int(lx0), 63));
    float wy0 = __int_as_float(__builtin_amdgcn_readlane(__float_as_int(ly0), 63));
    float wx1 = __int_as_float(__builtin_amdgcn_readlane(__float_as_int(lx1), 63));
    float wy1 = __int_as_float(__builtin_amdgcn_readlane(__float_as_int(ly1), 63));

    // one-time 64-lane-parallel truth-vs-wave-bbox test -> wave-uniform mask
    u64 smask;
    {
        int lane = tid & 63;
        bool sv = false;
        if (lane < OO) {
            float4 tt = trP[lane];
            sv = (tt.z > wx0 && tt.x < wx1 && tt.w > wy0 && tt.y < wy1);
        }
        smask = __ballot(sv);
    }

    float rbv[T1]; int rbi[T1];
#pragma unroll
    for (int j = 0; j < T1; ++j) { rbv[j] = 0.0f; rbi[j] = 0; }

    for (u64 mm = smask; mm; mm &= mm - 1) {
        int t = (int)__ffsll((long long)mm) - 1;    // ascending t order
        float4 tP = trP[t];
        float aA = trQ[t].x;
        float I[T1];
#pragma unroll
        for (int j = 0; j < T1; ++j) {
            float ltx = fmaxf(tP.x, bx0[j]), lty = fmaxf(tP.y, by0[j]);
            float rbx = fminf(tP.z, bx1[j]), rby = fminf(tP.w, by1[j]);
            float wx = fmaxf(rbx - ltx, 0.f), wy = fmaxf(rby - lty, 0.f);
            I[j] = wx * wy;
        }
        bool anyl = (I[0] > 0.f) | (I[1] > 0.f) | (I[2] > 0.f) | (I[3] > 0.f);
        if (__any(anyl)) {
            float cbv = 0.0f; int cbo = omin;
#pragma unroll
            for (int j = 0; j < T1; ++j) {
                float v = I[j] / (aA + aB[j] - I[j]);
                if (v > rbv[j]) { rbv[j] = v; rbi[j] = t; }   // row: first-max
                if (v > cbv || (v == cbv && o_[j] < cbo)) { cbv = v; cbo = o_[j]; }
            }
            float x = cbv;
            WAVE_MAXF(x);
            float mvf = __int_as_float(__builtin_amdgcn_readlane(__float_as_int(x), 63));
            if (mvf > 0.0f) {
                u64 msk = __ballot(cbv == mvf);
                int ln = (int)__ffsll((long long)msk) - 1;
                int morig = __builtin_amdgcn_readlane(cbo, ln);
                u64 rest = msk & (msk - 1);
                while (rest) {            // rare: exact cross-lane ties
                    int l2 = (int)__ffsll((long long)rest) - 1;
                    int o2 = __builtin_amdgcn_readlane(cbo, l2);
                    morig = min(morig, o2);
                    rest &= rest - 1;
                }
                if ((tid & 63) == 0) {
                    u64 pk = ((u64)__float_as_uint(mvf) << 32) | (unsigned)(PP - morig);
                    atomicMax(&bpm[b * OO + t], pk);
                }
            }
        }
    }

    // ---- epilogue: loss for the un-forced matching; per-wave exponent hist ----
    size_t bbase = (size_t)b * PP;
    int hb = (tid >> 6) * NB_P0;       // this wave's sub-histogram
    float ll = 0.0f, plc = 0.0f; int np = 0;
    float outv[4]; unsigned pbyte = 0;
#pragma unroll
    for (int c = 0; c < T1; ++c) {
        int o = o_[c]; size_t bo = bbase + o;
        int ti = rbi[c]; float ov = rbv[c];
        float2 cf = ((const float2*)arm_conf)[bo];
        float c0 = cf.x, c1 = cf.y;
        float m = fmaxf(c0, c1);
        float lse = logf(expf(c0 - m) + expf(c1 - m)) + m;
        bool pos = (ov >= THRESH_F) && (trQ[ti].y >= 0.0f);
        float lc = lse - (pos ? c1 : c0);
        outv[c] = pos ? 0.0f : lc;
        pbyte |= (unsigned)((pos ? 0x80u : 0u) | (unsigned)ti) << (8 * c);
        unsigned u = __float_as_uint(outv[c]);
        atomicAdd(&hc[hb + (u >> 23)], 1);
        atomicAdd(&hs[hb + (u >> 23)], outv[c]);
        if (pos) {
            np++; plc += lc;
            float4 pr = ((const float4*)priors)[o];
            float4 ld = ((const float4*)arm_loc)[bo];
            const float4 tv = trP[ti];
            float tb4[4] = {tv.x, tv.y, tv.z, tv.w};
            ll += sl1enc(tb4, pr, ld);
        }
    }
    size_t bq = bbase + p0;
    ((float4*)lcmP)[bq >> 2] = make_float4(outv[0], outv[1], outv[2], outv[3]);
    ((unsigned*)bpiP)[bq >> 2] = pbyte;

    __syncthreads();
    {   // merge per-wave hists (one bin per thread)
        int cv = hc[tid] + hc[NB_P0 + tid] + hc[2*NB_P0 + tid] + hc[3*NB_P0 + tid];
        if (cv) {
            float sv = hs[tid] + hs[NB_P0 + tid] + hs[2*NB_P0 + tid] + hs[3*NB_P0 + tid];
            atomicAdd(&Hc0[b * NB_P0 + tid], cv);
            atomicAdd(&Hs0[b * NB_P0 + tid], sv);
        }
    }
    s1[tid] = ll; s2[tid] = plc; s3[tid] = np;
    __syncthreads();
    for (int st = 128; st > 0; st >>= 1) {
        if (tid < st) { s1[tid] += s1[tid+st]; s2[tid] += s2[tid+st]; s3[tid] += s3[tid+st]; }
        __syncthreads();
    }
    if (tid == 0) {
        pll[s * BB + b] = s1[0];
        pplc[s * BB + b] = s2[0];
        pnp[s * BB + b] = s3[0];
    }
}

// ---- K2: forced-match fixup (round-10 version: emits COMPLETE per-batch
// sums llb/plcb/npb = partials + deltas; patches lcmP + hist). ----
__global__ void k_fix(const u64* __restrict__ bpm, const float* __restrict__ targets,
                      const float* __restrict__ arm_loc, const float* __restrict__ arm_conf,
                      const float* __restrict__ priors, const int* __restrict__ iperm,
                      const unsigned char* __restrict__ bpiP, float* __restrict__ lcmP,
                      const float* __restrict__ pll, const float* __restrict__ pplc,
                      const int* __restrict__ pnp,
                      float* __restrict__ llb, float* __restrict__ plcb,
                      int* __restrict__ npb,
                      int* __restrict__ Hc0, float* __restrict__ Hs0) {
    int b = blockIdx.x, j = threadIdx.x;   // 64 threads, one wave
    int p = -1;
    if (j < OO) {
        unsigned lo = (unsigned)(bpm[b * OO + j] & 0xFFFFFFFFull);
        p = lo ? (PP - (int)lo) : 0;   // all-zero column -> first prior
    }
    bool w = (j < OO);
    for (int jj = 1; jj < OO; ++jj) {
        int pj = __shfl(p, jj, 64);
        if (jj > j && pj == p) w = false;
    }
    float dll = 0.f, dplc = 0.f; int dnp = 0;
    if (w) {
        int pos_ = iperm[p];
        size_t bq = (size_t)b * PP + pos_;   // permuted (lcm/bpi) address
        size_t bo = (size_t)b * PP + p;      // original (conf/loc) address
        unsigned char ob = bpiP[bq];
        bool old_pos = (ob & 0x80u) != 0;
        int old_ti = ob & 63;
        float2 cf = ((const float2*)arm_conf)[bo];
        float c0 = cf.x, c1 = cf.y;
        float m = fmaxf(c0, c1);
        float lse = logf(expf(c0 - m) + expf(c1 - m)) + m;
        const float* tbj = &targets[(size_t)(b * OO + j) * 5];
        bool new_pos = (tbj[4] >= 0.0f);
        float old_lcm = lcmP[bq];
        float new_lcm = new_pos ? 0.0f : (lse - c0);
        unsigned uo = __float_as_uint(old_lcm), un = __float_as_uint(new_lcm);
        if (uo != un) {
            atomicAdd(&Hc0[b * NB_P0 + (uo >> 23)], -1);
            atomicAdd(&Hs0[b * NB_P0 + (uo >> 23)], -old_lcm);
            atomicAdd(&Hc0[b * NB_P0 + (un >> 23)], 1);
            atomicAdd(&Hs0[b * NB_P0 + (un >> 23)], new_lcm);
            lcmP[bq] = new_lcm;
        }
        float4 pr = ((const float4*)priors)[p];
        float4 ld = ((const float4*)arm_loc)[bo];
        if (old_pos) {
            dnp -= 1; dplc -= (lse - c1);
            dll -= sl1enc(&targets[(size_t)(b * OO + old_ti) * 5], pr, ld);
        }
        if (new_pos) {
            dnp += 1; dplc += (lse - c1);
            dll += sl1enc(tbj, pr, ld);
        }
    }
    float myll = (j < SS) ? pll[j * BB + b] : 0.f;
    float mypl = (j < SS) ? pplc[j * BB + b] : 0.f;
    int   mynp = (j < SS) ? pnp[j * BB + b] : 0;
    dll += myll; dplc += mypl; dnp += mynp;
    for (int st = 32; st >= 1; st >>= 1) {
        dll += __shfl_down(dll, st, 64);
        dplc += __shfl_down(dplc, st, 64);
        dnp += __shfl_down(dnp, st, 64);
    }
    if (j == 0) {
        llb[b] = dll;
        plcb[b] = dplc;
        npb[b] = dnp;
    }
}

// ---- K3: 3-pass radix selection (MLP-batched streams) + final cross-batch
// reduction via hardened ticket (round-10 proven). ----
__global__ void __launch_bounds__(256)
k_sel(const float* __restrict__ lcmP,
      const float* __restrict__ llb, const float* __restrict__ plcb,
      const int* __restrict__ npb,
      const int* __restrict__ Hc0, const float* __restrict__ Hs0,
      float* __restrict__ gacc, int* __restrict__ gcnt,
      float* __restrict__ out) {
    __shared__ int hc[NB_P1]; __shared__ float hs[NB_P1];
    __shared__ int sc[256]; __shared__ float sf[256];
    __shared__ int s_chunk, s_r; __shared__ float s_S; __shared__ unsigned s_pref;
    int b = blockIdx.x, tid = threadIdx.x;
    const float4* v4 = (const float4*)(lcmP + (size_t)b * PP);

    {   // pass 0: scan 256-bin global exponent hist (one bin per thread)
        int c = Hc0[b * NB_P0 + tid];
        float f = Hs0[b * NB_P0 + tid];
        sc[tid] = c; sf[tid] = f;
        if (tid == 0) {
            int k = NEGPOS_I * npb[b]; if (k > PP - 1) k = PP - 1;
            s_r = k; s_S = 0.f;
        }
        __syncthreads();
        for (int off = 1; off < 256; off <<= 1) {
            int cv = (tid + off < 256) ? sc[tid + off] : 0;
            float fv = (tid + off < 256) ? sf[tid + off] : 0.f;
            __syncthreads(); sc[tid] += cv; sf[tid] += fv; __syncthreads();
        }
        int r = s_r;
        int nxt = (tid == 255) ? 0 : sc[tid + 1];
        if (sc[tid] >= r && nxt < r) s_chunk = tid;
        __syncthreads();
        if (tid == 0) {
            int ch = s_chunk;
            s_pref = (unsigned)ch;
            s_r = r - ((ch == 255) ? 0 : sc[ch + 1]);
            s_S = (ch == 255) ? 0.f : sf[ch + 1];
        }
        __syncthreads();
    }
    {   // pass 1: bits 22:11 (4096 bins) where exponent byte == pref
        for (int i = tid; i < NB_P1; i += 256) { hc[i] = 0; hs[i] = 0.f; }
        __syncthreads();
        unsigned pref = s_pref;
        for (int it = 0; it < 8; ++it) {
            float4 xs4[4];
#pragma unroll
            for (int q = 0; q < 4; ++q) xs4[q] = v4[it * 1024 + q * 256 + tid];
#pragma unroll
            for (int q = 0; q < 4; ++q) {
                float xs[4] = {xs4[q].x, xs4[q].y, xs4[q].z, xs4[q].w};
                for (int c2 = 0; c2 < 4; ++c2) {
                    unsigned u = __float_as_uint(xs[c2]);
                    if ((u >> 23) == pref) {
                        atomicAdd(&hc[(u >> 11) & 4095u], 1);
                        atomicAdd(&hs[(u >> 11) & 4095u], xs[c2]);
                    }
                }
            }
        }
        __syncthreads();
        int c = 0; float f = 0.f; int base = tid * 16;
        for (int i = 0; i < 16; ++i) { c += hc[base + i]; f += hs[base + i]; }
        sc[tid] = c; sf[tid] = f; __syncthreads();
        for (int off = 1; off < 256; off <<= 1) {
            int cv = (tid + off < 256) ? sc[tid + off] : 0;
            float fv = (tid + off < 256) ? sf[tid + off] : 0.f;
            __syncthreads(); sc[tid] += cv; sf[tid] += fv; __syncthreads();
        }
        int r = s_r;
        int nxt = (tid == 255) ? 0 : sc[tid + 1];
        if (sc[tid] >= r && nxt < r) s_chunk = tid;
        __syncthreads();
        if (tid == 0) {
            int ch = s_chunk;
            int r2 = r - ((ch == 255) ? 0 : sc[ch + 1]);
            float S2 = s_S + ((ch == 255) ? 0.f : sf[ch + 1]);
            int binSel = ch * 16;
            for (int i = 15; i >= 0; --i) {
                int bin = ch * 16 + i; int cbn = hc[bin];
                if (r2 <= cbn) { binSel = bin; break; }
                r2 -= cbn; S2 += hs[bin];
            }
            s_pref = (s_pref << 12) | (unsigned)binSel; s_r = r2; s_S = S2;
        }
        __syncthreads();
    }
    {   // pass 2: bits 10:0 (2048 bins) where bits 30:11 == pref + ticket
        for (int i = tid; i < NB_P2; i += 256) { hc[i] = 0; hs[i] = 0.f; }
        __syncthreads();
        unsigned pref = s_pref;
        for (int it = 0; it < 8; ++it) {
            float4 xs4[4];
#pragma unroll
            for (int q = 0; q < 4; ++q) xs4[q] = v4[it * 1024 + q * 256 + tid];
#pragma unroll
            for (int q = 0; q < 4; ++q) {
                float xs[4] = {xs4[q].x, xs4[q].y, xs4[q].z, xs4[q].w};
                for (int c2 = 0; c2 < 4; ++c2) {
                    unsigned u = __float_as_uint(xs[c2]);
                    if ((u >> 11) == pref) {
                        atomicAdd(&hc[u & 2047u], 1);
                        atomicAdd(&hs[u & 2047u], xs[c2]);
                    }
                }
            }
        }
        __syncthreads();
        int c = 0; float f = 0.f; int base = tid * 8;
        for (int i = 0; i < 8; ++i) { c += hc[base + i]; f += hs[base + i]; }
        sc[tid] = c; sf[tid] = f; __syncthreads();
        for (int off = 1; off < 256; off <<= 1) {
            int cv = (tid + off < 256) ? sc[tid + off] : 0;
            float fv = (tid + off < 256) ? sf[tid + off] : 0.f;
            __syncthreads(); sc[tid] += cv; sf[tid] += fv; __syncthreads();
        }
        int r = s_r;
        int nxt = (tid == 255) ? 0 : sc[tid + 1];
        if (sc[tid] >= r && nxt < r) s_chunk = tid;
        __syncthreads();
        if (tid == 0) {
            int ch = s_chunk;
            int r2 = r - ((ch == 255) ? 0 : sc[ch + 1]);
            float S2 = s_S + ((ch == 255) ? 0.f : sf[ch + 1]);
            int binSel = ch * 8;
            for (int i = 7; i >= 0; --i) {
                int bin = ch * 8 + i; int cbn = hc[bin];
                if (r2 <= cbn) { binSel = bin; break; }
                r2 -= cbn; S2 += hs[bin];
            }
            unsigned tb = (s_pref << 11) | (unsigned)binSel;
            float tval = __uint_as_float(tb);
            float ccb = plcb[b] + S2 + (float)r2 * tval;
            float llv = llb[b]; int npv = npb[b];
            atomicAdd(&gacc[0], llv);
            atomicAdd(&gacc[1], ccb);
            atomicAdd(&gcnt[0], npv);
            __threadfence();
            int tk = atomicAdd(&gcnt[1], 1);
            if (tk == BB - 1) {
                __threadfence();
                float llt = atomicAdd(&gacc[0], 0.f);   // coherent re-read
                float cct = atomicAdd(&gacc[1], 0.f);
                int npt = atomicAdd(&gcnt[0], 0);
                float N = (float)npt;
                out[0] = llt / N;
                out[1] = cct / N;
            }
        }
    }
}

extern "C" void kernel_launch(void* const* d_in, const int* in_sizes, int n_in,
                              void* d_out, int out_size, void* d_ws, size_t ws_size,
                              hipStream_t stream) {
    const float* arm_loc  = (const float*)d_in[0];
    const float* arm_conf = (const float*)d_in[1];
    const float* priors   = (const float*)d_in[4];
    const float* targets  = (const float*)d_in[5];
    float* out = (float*)d_out;

    char* w = (char*)d_ws;
    float* lcmP = (float*)w;  w += sizeof(float) * (size_t)BB * PP;   // 8 MB
    unsigned char* bpiP = (unsigned char*)w; w += (size_t)BB * PP;    // 2 MB
    // ---- zeroed-by-k_pss region (atomically accumulated later) ----
    char* zbase = w;
    int*   Hc0 = (int*)w;    w += sizeof(int)   * BB * NB_P0;
    float* Hs0 = (float*)w;  w += sizeof(float) * BB * NB_P0;
    u64*   bpm = (u64*)w;    w += sizeof(u64)   * BB * OO;
    float* gacc = (float*)w; w += sizeof(float) * 2;   // ll, cc totals
    int*   gcnt = (int*)w;   w += sizeof(int)   * 2;   // np total, ticket
    size_t zbytes = (size_t)(w - zbase);
    // ---- plain written-before-read region ----
    int*   cnt32 = (int*)w;  w += sizeof(int) * 32 * NCELL;
    int*   cursor = (int*)w; w += sizeof(int) * NCELL;
    int*   perm  = (int*)w;  w += sizeof(int) * PP;
    int*   iperm = (int*)w;  w += sizeof(int) * PP;
    float* pll  = (float*)w; w += sizeof(float) * BB * SS;
    float* pplc = (float*)w; w += sizeof(float) * BB * SS;
    int*   pnp  = (int*)w;   w += sizeof(int)   * BB * SS;
    float* llb  = (float*)w; w += sizeof(float) * BB;
    float* plcb = (float*)w; w += sizeof(float) * BB;
    int*   npb  = (int*)w;   w += sizeof(int)   * BB;

    int zn4 = (int)(zbytes / 16);
    k_phist<<<PP / 1024, 256, 0, stream>>>((const float4*)priors, cnt32, cursor);
    k_pss<<<PP / 1024, 256, 0, stream>>>((const float4*)priors, cnt32, cursor,
                                         perm, iperm, (float4*)zbase, zn4);
    k_ml<<<dim3(SS, BB), 256, 0, stream>>>(priors, perm, targets, arm_loc, arm_conf,
                                           lcmP, bpiP, bpm, pll, pplc, pnp, Hc0, Hs0);
    k_fix<<<BB, 64, 0, stream>>>(bpm, targets, arm_loc, arm_conf, priors, iperm,
                                 bpiP, lcmP, pll, pplc, pnp, llb, plcb, npb, Hc0, Hs0);
    k_sel<<<BB, 256, 0, stream>>>(lcmP, llb, plcb, npb, Hc0, Hs0, gacc, gcnt, out);
}